// Round 2
// baseline (314.281 us; speedup 1.0000x reference)
//
#include <hip/hip_runtime.h>

// KNRM fused, round 2: doc-split for occupancy/latency hiding.
// Grid = B(256) x DSPLIT(8) blocks, 256 threads. Each block: stage q-tile
// (32x320 bf16) + one d-tile (64x320 bf16) with a SINGLE barrier, MFMA
// 16x16x32 bf16 cosine matmul, Gaussian kernels on accumulator regs,
// lane-shuffle reduction, global atomicAdd into pkq[B,32,11] in d_ws.
// Epilogue kernel: log/mask/dot -> out[B].
// Numerics: reciprocal norms from bf16-ROUNDED embeddings so exact-match
// pairs give cosine == 1 (kernel0 sigma=1e-4).

#define B     256
#define BQ    32
#define BD    512
#define EDIM  300
#define KPAD  320
#define NK    11
#define DTILE 64
#define DSPLIT (BD / DTILE)     // 8
#define QS    328               // LDS row stride (bf16): 164 words == 4 mod 32
#define DSTR  328

typedef float  floatx4 __attribute__((ext_vector_type(4)));
typedef short  shortx8 __attribute__((ext_vector_type(8)));

__device__ __forceinline__ unsigned short f2bf(float f) {
    unsigned int u = __float_as_uint(f);
    unsigned int r = (u + 0x7fffu + ((u >> 16) & 1u)) >> 16;  // RNE
    return (unsigned short)r;
}
__device__ __forceinline__ float bf2f(unsigned short h) {
    return __uint_as_float(((unsigned int)h) << 16);
}

__global__ __launch_bounds__(256)
void knrm_main(const int* __restrict__ qtok, const int* __restrict__ dtok,
               const float* __restrict__ emb, const float* __restrict__ mu,
               const float* __restrict__ sigma, float* __restrict__ pkq_g)
{
    __shared__ unsigned short q_buf[BQ * QS];
    __shared__ unsigned short d_buf[DTILE * DSTR];
    __shared__ float rqs[BQ];
    __shared__ float rds[DTILE], dms[DTILE];

    const int tid   = threadIdx.x;
    const int b     = blockIdx.x >> 3;      // batch
    const int chunk = blockIdx.x & 7;       // which 64-doc chunk

    // ---- gaussian constants (uniform -> scalar loads) ----
    float mur[NK], cfr[NK];
    #pragma unroll
    for (int k = 0; k < NK; ++k) {
        float s = sigma[k];
        mur[k] = mu[k];
        cfr[k] = -0.5f / (s * s);
    }

    // ---- zero the K-pad region [300,320) ----
    for (int i = tid; i < BQ * (KPAD - EDIM); i += 256) {
        int r = i / (KPAD - EDIM), j = i - r * (KPAD - EDIM);
        q_buf[r * QS + EDIM + j] = 0;
    }
    for (int i = tid; i < DTILE * (KPAD - EDIM); i += 256) {
        int r = i / (KPAD - EDIM), j = i - r * (KPAD - EDIM);
        d_buf[r * DSTR + EDIM + j] = 0;
    }

    // ---- stage query tile: 8 threads per row (no barrier before d stage) ----
    {
        int row = tid >> 3, part = tid & 7;
        int tok = qtok[b * BQ + row];
        const float4* src = (const float4*)(emb + (size_t)tok * EDIM);
        float ss = 0.f;
        for (int i = part; i < EDIM / 4; i += 8) {
            float4 v = src[i];
            unsigned short h0 = f2bf(v.x), h1 = f2bf(v.y), h2 = f2bf(v.z), h3 = f2bf(v.w);
            uint2 p;
            p.x = (unsigned int)h0 | ((unsigned int)h1 << 16);
            p.y = (unsigned int)h2 | ((unsigned int)h3 << 16);
            *(uint2*)&q_buf[row * QS + i * 4] = p;
            float f0 = bf2f(h0), f1 = bf2f(h1), f2 = bf2f(h2), f3 = bf2f(h3);
            ss += f0 * f0 + f1 * f1 + f2 * f2 + f3 * f3;
        }
        ss += __shfl_xor(ss, 1);
        ss += __shfl_xor(ss, 2);
        ss += __shfl_xor(ss, 4);
        if (part == 0) rqs[row] = 1.f / (sqrtf(ss) + 1e-13f);
    }

    // ---- stage doc tile: 4 threads per row ----
    {
        int row = tid >> 2, part = tid & 3;
        int tok = dtok[b * BD + chunk * DTILE + row];
        const float4* src = (const float4*)(emb + (size_t)tok * EDIM);
        float ss = 0.f;
        for (int i = part; i < EDIM / 4; i += 4) {
            float4 v = src[i];
            unsigned short h0 = f2bf(v.x), h1 = f2bf(v.y), h2 = f2bf(v.z), h3 = f2bf(v.w);
            uint2 p;
            p.x = (unsigned int)h0 | ((unsigned int)h1 << 16);
            p.y = (unsigned int)h2 | ((unsigned int)h3 << 16);
            *(uint2*)&d_buf[row * DSTR + i * 4] = p;
            float f0 = bf2f(h0), f1 = bf2f(h1), f2 = bf2f(h2), f3 = bf2f(h3);
            ss += f0 * f0 + f1 * f1 + f2 * f2 + f3 * f3;
        }
        ss += __shfl_xor(ss, 1);
        ss += __shfl_xor(ss, 2);
        if (part == 0) {
            rds[row] = 1.f / (sqrtf(ss) + 1e-13f);
            dms[row] = (tok > 0) ? 1.f : 0.f;
        }
    }
    __syncthreads();

    // ---- per-wave MFMA tile: wave (mbase, nbase) covers 16q x 32d ----
    const int lane  = tid & 63;
    const int wv    = tid >> 6;
    const int l16   = lane & 15;
    const int quad  = lane >> 4;
    const int mbase = (wv & 1) * 16;
    const int nbase = (wv >> 1) * 32;

    const unsigned short* aptr  = &q_buf[(mbase + l16) * QS + quad * 8];
    const unsigned short* b0ptr = &d_buf[(nbase + l16) * DSTR + quad * 8];
    const unsigned short* b1ptr = b0ptr + 16 * DSTR;

    floatx4 acc0 = {0.f, 0.f, 0.f, 0.f};
    floatx4 acc1 = {0.f, 0.f, 0.f, 0.f};
    #pragma unroll
    for (int ks = 0; ks < KPAD / 32; ++ks) {
        shortx8 a  = *(const shortx8*)(aptr  + ks * 32);
        shortx8 b0 = *(const shortx8*)(b0ptr + ks * 32);
        shortx8 b1 = *(const shortx8*)(b1ptr + ks * 32);
        acc0 = __builtin_amdgcn_mfma_f32_16x16x32_bf16(a, b0, acc0, 0, 0, 0);
        acc1 = __builtin_amdgcn_mfma_f32_16x16x32_bf16(a, b1, acc1, 0, 0, 0);
    }

    // ---- Gaussians on accumulators, shuffle-reduce over the 16 doc lanes,
    //      one global atomic per (q,k) per wave ----
    float rqv[4];
    #pragma unroll
    for (int r = 0; r < 4; ++r) rqv[r] = rqs[mbase + quad * 4 + r];
    float rd0 = rds[nbase + l16],      dm0 = dms[nbase + l16];
    float rd1 = rds[nbase + 16 + l16], dm1 = dms[nbase + 16 + l16];

    #pragma unroll
    for (int r = 0; r < 4; ++r) {
        float c0 = acc0[r] * rqv[r] * rd0;
        float c1 = acc1[r] * rqv[r] * rd1;
        int q = mbase + quad * 4 + r;
        #pragma unroll
        for (int k = 0; k < NK; ++k) {
            float d0 = c0 - mur[k];
            float d1 = c1 - mur[k];
            float v = dm0 * __expf(cfr[k] * d0 * d0)
                    + dm1 * __expf(cfr[k] * d1 * d1);
            v += __shfl_xor(v, 1);
            v += __shfl_xor(v, 2);
            v += __shfl_xor(v, 4);
            v += __shfl_xor(v, 8);
            if (l16 == 0) atomicAdd(&pkq_g[(b * BQ + q) * NK + k], v);
        }
    }
}

__global__ __launch_bounds__(64)
void knrm_epilogue(const int* __restrict__ qtok, const float* __restrict__ dw,
                   const float* __restrict__ db, const float* __restrict__ pkq_g,
                   float* __restrict__ out)
{
    int b = blockIdx.x, lane = threadIdx.x;
    float sq = 0.f;
    if (lane < BQ) {
        int tok = qtok[b * BQ + lane];
        if (tok > 0) {
            const float* p = &pkq_g[(b * BQ + lane) * NK];
            #pragma unroll
            for (int k = 0; k < NK; ++k) {
                float v = fmaxf(p[k], 1e-10f);
                sq += __logf(v) * 0.01f * dw[k];
            }
        }
    }
    sq += __shfl_xor(sq, 1);
    sq += __shfl_xor(sq, 2);
    sq += __shfl_xor(sq, 4);
    sq += __shfl_xor(sq, 8);
    sq += __shfl_xor(sq, 16);
    sq += __shfl_xor(sq, 32);
    if (lane == 0) out[b] = sq + db[0];
}

extern "C" void kernel_launch(void* const* d_in, const int* in_sizes, int n_in,
                              void* d_out, int out_size, void* d_ws, size_t ws_size,
                              hipStream_t stream)
{
    const int*   qtok  = (const int*)d_in[0];
    const int*   dtok  = (const int*)d_in[1];
    const float* emb   = (const float*)d_in[2];
    const float* dw    = (const float*)d_in[3];
    const float* dbias = (const float*)d_in[4];
    const float* mu    = (const float*)d_in[5];
    const float* sg    = (const float*)d_in[6];
    float* out   = (float*)d_out;
    float* pkq_g = (float*)d_ws;               // B*BQ*NK floats = 360448 B

    hipMemsetAsync(pkq_g, 0, (size_t)B * BQ * NK * sizeof(float), stream);
    knrm_main<<<B * DSPLIT, 256, 0, stream>>>(qtok, dtok, emb, mu, sg, pkq_g);
    knrm_epilogue<<<B, 64, 0, stream>>>(qtok, dw, dbias, pkq_g, out);
}

// Round 3
// 253.094 us; speedup vs baseline: 1.2418x; 1.2418x over previous
//
#include <hip/hip_runtime.h>

// KNRM round 3: two-phase.
//  Phase 1 (knrm_norm): streaming pass over the whole emb table ->
//    bf16 rows padded to 320 cols (zeros in [300,320)) + reciprocal norms
//    computed FROM the bf16-rounded values (exact-match => cosine==1, which
//    kernel0 sigma=1e-4 requires). Lives in d_ws.
//  Phase 2 (knrm_main2): grid = B(256) x DSPLIT(8). Pure 640B-row bf16
//    gather -> LDS, MFMA 16x16x32 cosine, Gaussians on acc regs, block-local
//    LDS reduction, contention-free partial stores pkq_part[b][chunk][32][11].
//  Phase 3 (knrm_epi2): sum chunk partials, log/mask/dot -> out[B].
// Fallback: if ws_size < ~68 MB, run the round-1 monolithic kernel (needs no ws).

#define B     256
#define BQ    32
#define BD    512
#define EDIM  300
#define KPAD  320
#define NK    11
#define DTILE 64
#define DSPLIT (BD / DTILE)     // 8
#define QS    328               // LDS row stride (bf16): 164 words == 4 mod 32
#define DSTR  328

typedef float  floatx4 __attribute__((ext_vector_type(4)));
typedef short  shortx8 __attribute__((ext_vector_type(8)));

__device__ __forceinline__ unsigned short f2bf(float f) {
    unsigned int u = __float_as_uint(f);
    unsigned int r = (u + 0x7fffu + ((u >> 16) & 1u)) >> 16;  // RNE
    return (unsigned short)r;
}
__device__ __forceinline__ float bf2f(unsigned short h) {
    return __uint_as_float(((unsigned int)h) << 16);
}

// ---------------- Phase 1: normalize / convert table ----------------
// 16 lanes per row, 16 rows per 256-thread block.
__global__ __launch_bounds__(256)
void knrm_norm(const float* __restrict__ emb, unsigned short* __restrict__ ebf,
               float* __restrict__ rnorm, int V)
{
    int r    = blockIdx.x * 16 + (threadIdx.x >> 4);
    int part = threadIdx.x & 15;
    if (r >= V) return;
    const float4* src = (const float4*)(emb + (size_t)r * EDIM);
    uint2*        dst = (uint2*)(ebf + (size_t)r * KPAD);
    float ss = 0.f;
    #pragma unroll
    for (int i = 0; i < 5; ++i) {
        int c = part + i * 16;            // 0..79 covers 80 uint2 = 640 B
        uint2 p = {0u, 0u};
        if (c < EDIM / 4) {               // 75 real float4 chunks
            float4 v = src[c];
            unsigned short h0 = f2bf(v.x), h1 = f2bf(v.y), h2 = f2bf(v.z), h3 = f2bf(v.w);
            p.x = (unsigned int)h0 | ((unsigned int)h1 << 16);
            p.y = (unsigned int)h2 | ((unsigned int)h3 << 16);
            float f0 = bf2f(h0), f1 = bf2f(h1), f2 = bf2f(h2), f3 = bf2f(h3);
            ss += f0 * f0 + f1 * f1 + f2 * f2 + f3 * f3;
        }
        dst[c] = p;                       // pad chunks write zeros
    }
    ss += __shfl_xor(ss, 1);
    ss += __shfl_xor(ss, 2);
    ss += __shfl_xor(ss, 4);
    ss += __shfl_xor(ss, 8);
    if (part == 0) rnorm[r] = 1.f / (sqrtf(ss) + 1e-13f);
}

// ---------------- Phase 2: gather + MFMA + Gaussians ----------------
__global__ __launch_bounds__(256)
void knrm_main2(const int* __restrict__ qtok, const int* __restrict__ dtok,
                const unsigned short* __restrict__ ebf, const float* __restrict__ rnorm,
                const float* __restrict__ mu, const float* __restrict__ sigma,
                float* __restrict__ pkq_part)
{
    __shared__ unsigned short q_buf[BQ * QS];
    __shared__ unsigned short d_buf[DTILE * DSTR];
    __shared__ float rqs[BQ];
    __shared__ float rds[DTILE], dms[DTILE];
    __shared__ float pkq_s[BQ * NK];

    const int tid   = threadIdx.x;
    const int b     = blockIdx.x >> 3;
    const int chunk = blockIdx.x & 7;

    float mur[NK], cfr[NK];
    #pragma unroll
    for (int k = 0; k < NK; ++k) {
        float s = sigma[k];
        mur[k] = mu[k];
        cfr[k] = -0.5f / (s * s);
    }

    for (int i = tid; i < BQ * NK; i += 256) pkq_s[i] = 0.f;

    // per-row reciprocal norms + doc mask
    if (tid < DTILE) {
        int tok = dtok[b * BD + chunk * DTILE + tid];
        rds[tid] = rnorm[tok];
        dms[tid] = (tok > 0) ? 1.f : 0.f;
    } else if (tid < DTILE + BQ) {
        int r = tid - DTILE;
        int tok = qtok[b * BQ + r];
        rqs[r] = rnorm[tok];
    }

    // q tile: 8 threads/row x 5 uint4 (row = 640 B)
    {
        int row = tid >> 3, part = tid & 7;
        int tok = qtok[b * BQ + row];
        const uint4* src = (const uint4*)(ebf + (size_t)tok * KPAD);
        #pragma unroll
        for (int i = 0; i < 5; ++i) {
            int c = part + i * 8;
            uint4 v = src[c];
            *(uint4*)&q_buf[row * QS + c * 8] = v;
        }
    }
    // d tile: 4 threads/row x 10 uint4
    {
        int row = tid >> 2, part = tid & 3;
        int tok = dtok[b * BD + chunk * DTILE + row];
        const uint4* src = (const uint4*)(ebf + (size_t)tok * KPAD);
        #pragma unroll
        for (int i = 0; i < 10; ++i) {
            int c = part + i * 4;
            uint4 v = src[c];
            *(uint4*)&d_buf[row * DSTR + c * 8] = v;
        }
    }
    __syncthreads();

    const int lane  = tid & 63;
    const int wv    = tid >> 6;
    const int l16   = lane & 15;
    const int quad  = lane >> 4;
    const int mbase = (wv & 1) * 16;
    const int nbase = (wv >> 1) * 32;

    const unsigned short* aptr  = &q_buf[(mbase + l16) * QS + quad * 8];
    const unsigned short* b0ptr = &d_buf[(nbase + l16) * DSTR + quad * 8];
    const unsigned short* b1ptr = b0ptr + 16 * DSTR;

    floatx4 acc0 = {0.f, 0.f, 0.f, 0.f};
    floatx4 acc1 = {0.f, 0.f, 0.f, 0.f};
    #pragma unroll
    for (int ks = 0; ks < KPAD / 32; ++ks) {
        shortx8 a  = *(const shortx8*)(aptr  + ks * 32);
        shortx8 b0 = *(const shortx8*)(b0ptr + ks * 32);
        shortx8 b1 = *(const shortx8*)(b1ptr + ks * 32);
        acc0 = __builtin_amdgcn_mfma_f32_16x16x32_bf16(a, b0, acc0, 0, 0, 0);
        acc1 = __builtin_amdgcn_mfma_f32_16x16x32_bf16(a, b1, acc1, 0, 0, 0);
    }

    float rqv[4];
    #pragma unroll
    for (int r = 0; r < 4; ++r) rqv[r] = rqs[mbase + quad * 4 + r];
    float rd0 = rds[nbase + l16],      dm0 = dms[nbase + l16];
    float rd1 = rds[nbase + 16 + l16], dm1 = dms[nbase + 16 + l16];

    #pragma unroll
    for (int r = 0; r < 4; ++r) {
        float c0 = acc0[r] * rqv[r] * rd0;
        float c1 = acc1[r] * rqv[r] * rd1;
        int q = mbase + quad * 4 + r;
        #pragma unroll
        for (int k = 0; k < NK; ++k) {
            float d0 = c0 - mur[k];
            float d1 = c1 - mur[k];
            float v = dm0 * __expf(cfr[k] * d0 * d0)
                    + dm1 * __expf(cfr[k] * d1 * d1);
            v += __shfl_xor(v, 1);
            v += __shfl_xor(v, 2);
            v += __shfl_xor(v, 4);
            v += __shfl_xor(v, 8);
            if (l16 == 0) atomicAdd(&pkq_s[q * NK + k], v);   // LDS atomic, 2-way
        }
    }
    __syncthreads();

    float* dst = &pkq_part[(size_t)blockIdx.x * (BQ * NK)];
    for (int i = tid; i < BQ * NK; i += 256) dst[i] = pkq_s[i];
}

// ---------------- Phase 3: epilogue ----------------
__global__ __launch_bounds__(64)
void knrm_epi2(const int* __restrict__ qtok, const float* __restrict__ dw,
               const float* __restrict__ db, const float* __restrict__ pkq_part,
               float* __restrict__ out)
{
    int b = blockIdx.x, lane = threadIdx.x;
    float sq = 0.f;
    if (lane < BQ) {
        int tok = qtok[b * BQ + lane];
        if (tok > 0) {
            #pragma unroll
            for (int k = 0; k < NK; ++k) {
                float s = 0.f;
                #pragma unroll
                for (int c = 0; c < DSPLIT; ++c)
                    s += pkq_part[((size_t)(b * DSPLIT + c) * BQ + lane) * NK + k];
                sq += __logf(fmaxf(s, 1e-10f)) * 0.01f * dw[k];
            }
        }
    }
    sq += __shfl_xor(sq, 1);
    sq += __shfl_xor(sq, 2);
    sq += __shfl_xor(sq, 4);
    sq += __shfl_xor(sq, 8);
    sq += __shfl_xor(sq, 16);
    sq += __shfl_xor(sq, 32);
    if (lane == 0) out[b] = sq + db[0];
}

// ---------------- Fallback: round-1 monolithic kernel (no ws) ----------------
__global__ __launch_bounds__(256)
void knrm_mono(const int* __restrict__ qtok, const int* __restrict__ dtok,
               const float* __restrict__ emb, const float* __restrict__ dw,
               const float* __restrict__ db, const float* __restrict__ mu,
               const float* __restrict__ sigma, float* __restrict__ out)
{
    __shared__ unsigned short q_buf[BQ * QS];
    __shared__ unsigned short d_buf[DTILE * DSTR];
    __shared__ float rqs[BQ], qms[BQ];
    __shared__ float rds[DTILE], dms[DTILE];
    __shared__ float pkq[BQ * NK];
    __shared__ float muS[NK], cfS[NK], wS[NK];
    __shared__ float red[BQ];

    const int tid = threadIdx.x;
    const int b   = blockIdx.x;

    if (tid < NK) {
        float s = sigma[tid];
        muS[tid] = mu[tid];
        cfS[tid] = -0.5f / (s * s);
        wS[tid]  = dw[tid];
    }
    for (int i = tid; i < BQ * NK; i += 256) pkq[i] = 0.f;
    for (int i = tid; i < BQ * (KPAD - EDIM); i += 256) {
        int r = i / (KPAD - EDIM), j = i - r * (KPAD - EDIM);
        q_buf[r * QS + EDIM + j] = 0;
    }
    for (int i = tid; i < DTILE * (KPAD - EDIM); i += 256) {
        int r = i / (KPAD - EDIM), j = i - r * (KPAD - EDIM);
        d_buf[r * DSTR + EDIM + j] = 0;
    }
    {
        int row = tid >> 3, part = tid & 7;
        int tok = qtok[b * BQ + row];
        const float4* src = (const float4*)(emb + (size_t)tok * EDIM);
        float ss = 0.f;
        for (int i = part; i < EDIM / 4; i += 8) {
            float4 v = src[i];
            unsigned short h0 = f2bf(v.x), h1 = f2bf(v.y), h2 = f2bf(v.z), h3 = f2bf(v.w);
            uint2 p;
            p.x = (unsigned int)h0 | ((unsigned int)h1 << 16);
            p.y = (unsigned int)h2 | ((unsigned int)h3 << 16);
            *(uint2*)&q_buf[row * QS + i * 4] = p;
            float f0 = bf2f(h0), f1 = bf2f(h1), f2 = bf2f(h2), f3 = bf2f(h3);
            ss += f0 * f0 + f1 * f1 + f2 * f2 + f3 * f3;
        }
        ss += __shfl_xor(ss, 1);
        ss += __shfl_xor(ss, 2);
        ss += __shfl_xor(ss, 4);
        if (part == 0) {
            rqs[row] = 1.f / (sqrtf(ss) + 1e-13f);
            qms[row] = (tok > 0) ? 1.f : 0.f;
        }
    }
    __syncthreads();

    const int lane  = tid & 63;
    const int wv    = tid >> 6;
    const int l16   = lane & 15;
    const int quad  = lane >> 4;
    const int mbase = (wv & 1) * 16;
    const int nbase = (wv >> 1) * 32;

    float rqv[4];
    #pragma unroll
    for (int r = 0; r < 4; ++r) rqv[r] = rqs[mbase + quad * 4 + r];
    float mur[NK], cfr[NK];
    #pragma unroll
    for (int k = 0; k < NK; ++k) { mur[k] = muS[k]; cfr[k] = cfS[k]; }
    float pk[4][NK];
    #pragma unroll
    for (int r = 0; r < 4; ++r)
        #pragma unroll
        for (int k = 0; k < NK; ++k) pk[r][k] = 0.f;

    const unsigned short* aptr  = &q_buf[(mbase + l16) * QS + quad * 8];
    const unsigned short* b0ptr = &d_buf[(nbase + l16) * DSTR + quad * 8];
    const unsigned short* b1ptr = b0ptr + 16 * DSTR;

    for (int t = 0; t < BD / DTILE; ++t) {
        {
            int row = tid >> 2, part = tid & 3;
            int tok = dtok[b * BD + t * DTILE + row];
            const float4* src = (const float4*)(emb + (size_t)tok * EDIM);
            float ss = 0.f;
            for (int i = part; i < EDIM / 4; i += 4) {
                float4 v = src[i];
                unsigned short h0 = f2bf(v.x), h1 = f2bf(v.y), h2 = f2bf(v.z), h3 = f2bf(v.w);
                uint2 p;
                p.x = (unsigned int)h0 | ((unsigned int)h1 << 16);
                p.y = (unsigned int)h2 | ((unsigned int)h3 << 16);
                *(uint2*)&d_buf[row * DSTR + i * 4] = p;
                float f0 = bf2f(h0), f1 = bf2f(h1), f2 = bf2f(h2), f3 = bf2f(h3);
                ss += f0 * f0 + f1 * f1 + f2 * f2 + f3 * f3;
            }
            ss += __shfl_xor(ss, 1);
            ss += __shfl_xor(ss, 2);
            if (part == 0) {
                rds[row] = 1.f / (sqrtf(ss) + 1e-13f);
                dms[row] = (tok > 0) ? 1.f : 0.f;
            }
        }
        __syncthreads();

        floatx4 acc0 = {0.f, 0.f, 0.f, 0.f};
        floatx4 acc1 = {0.f, 0.f, 0.f, 0.f};
        #pragma unroll
        for (int ks = 0; ks < KPAD / 32; ++ks) {
            shortx8 a  = *(const shortx8*)(aptr  + ks * 32);
            shortx8 b0 = *(const shortx8*)(b0ptr + ks * 32);
            shortx8 b1 = *(const shortx8*)(b1ptr + ks * 32);
            acc0 = __builtin_amdgcn_mfma_f32_16x16x32_bf16(a, b0, acc0, 0, 0, 0);
            acc1 = __builtin_amdgcn_mfma_f32_16x16x32_bf16(a, b1, acc1, 0, 0, 0);
        }
        float rd0 = rds[nbase + l16],      dm0 = dms[nbase + l16];
        float rd1 = rds[nbase + 16 + l16], dm1 = dms[nbase + 16 + l16];
        #pragma unroll
        for (int r = 0; r < 4; ++r) {
            float c0 = acc0[r] * rqv[r] * rd0;
            float c1 = acc1[r] * rqv[r] * rd1;
            #pragma unroll
            for (int k = 0; k < NK; ++k) {
                float d0 = c0 - mur[k];
                float d1 = c1 - mur[k];
                pk[r][k] += dm0 * __expf(cfr[k] * d0 * d0)
                          + dm1 * __expf(cfr[k] * d1 * d1);
            }
        }
        __syncthreads();
    }
    #pragma unroll
    for (int r = 0; r < 4; ++r) {
        int q = mbase + quad * 4 + r;
        #pragma unroll
        for (int k = 0; k < NK; ++k) atomicAdd(&pkq[q * NK + k], pk[r][k]);
    }
    __syncthreads();
    if (tid < BQ) {
        float sq = 0.f;
        if (qms[tid] > 0.f) {
            #pragma unroll
            for (int k = 0; k < NK; ++k) {
                float v = fmaxf(pkq[tid * NK + k], 1e-10f);
                sq += __logf(v) * 0.01f * wS[k];
            }
        }
        red[tid] = sq;
    }
    __syncthreads();
    if (tid == 0) {
        float s = db[0];
        #pragma unroll 8
        for (int i = 0; i < BQ; ++i) s += red[i];
        out[b] = s;
    }
}

extern "C" void kernel_launch(void* const* d_in, const int* in_sizes, int n_in,
                              void* d_out, int out_size, void* d_ws, size_t ws_size,
                              hipStream_t stream)
{
    const int*   qtok  = (const int*)d_in[0];
    const int*   dtok  = (const int*)d_in[1];
    const float* emb   = (const float*)d_in[2];
    const float* dw    = (const float*)d_in[3];
    const float* dbias = (const float*)d_in[4];
    const float* mu    = (const float*)d_in[5];
    const float* sg    = (const float*)d_in[6];
    float* out = (float*)d_out;

    const int V = in_sizes[2] / EDIM;               // vocab rows (100000)
    const size_t ebf_bytes   = (size_t)V * KPAD * 2;          // bf16 table
    const size_t rn_bytes    = (size_t)V * 4;                 // rnorm
    const size_t pkq_bytes   = (size_t)B * DSPLIT * BQ * NK * 4;
    const size_t need        = ebf_bytes + rn_bytes + pkq_bytes;

    if (ws_size >= need) {
        unsigned short* ebf   = (unsigned short*)d_ws;
        float* rnorm          = (float*)((char*)d_ws + ebf_bytes);
        float* pkq_part       = (float*)((char*)d_ws + ebf_bytes + rn_bytes);
        knrm_norm<<<(V + 15) / 16, 256, 0, stream>>>(emb, ebf, rnorm, V);
        knrm_main2<<<B * DSPLIT, 256, 0, stream>>>(qtok, dtok, ebf, rnorm, mu, sg, pkq_part);
        knrm_epi2<<<B, 64, 0, stream>>>(qtok, dw, dbias, pkq_part, out);
    } else {
        knrm_mono<<<B, 256, 0, stream>>>(qtok, dtok, emb, dw, dbias, mu, sg, out);
    }
}